// Round 7
// baseline (719.576 us; speedup 1.0000x reference)
//
#include <hip/hip_runtime.h>
#include <type_traits>
#include <utility>
#include <stdint.h>
#include <stddef.h>

#define TOKENS 8192
#define CDIM 2048
#define FDIM 8192
#define EPSV 1.1920929e-07f

typedef __attribute__((ext_vector_type(8))) short short8;
typedef __attribute__((ext_vector_type(8))) __bf16 bf16x8;
typedef __attribute__((ext_vector_type(4))) float floatx4;
typedef __attribute__((ext_vector_type(4))) float f32x4;
typedef __attribute__((ext_vector_type(2))) unsigned int u32x2;

// Detect which operand typing this clang uses for the gfx950 bf16 MFMA builtin.
template <typename V, typename = void> struct CanMfma : std::false_type {};
template <typename V>
struct CanMfma<V, std::void_t<decltype(__builtin_amdgcn_mfma_f32_16x16x32_bf16(
    std::declval<V>(), std::declval<V>(), std::declval<floatx4>(), 0, 0, 0))>>
    : std::true_type {};
using frag_t = std::conditional_t<CanMfma<short8>::value, short8, bf16x8>;

__device__ __forceinline__ floatx4 mfma_bf16(frag_t a, frag_t b, floatx4 c) {
    return __builtin_amdgcn_mfma_f32_16x16x32_bf16(a, b, c, 0, 0, 0);
}

// round-to-nearest-even f32 -> bf16
__device__ __forceinline__ unsigned short f2bf(float f) {
    unsigned int u = __float_as_uint(f);
    u += 0x7fffu + ((u >> 16) & 1u);
    return (unsigned short)(u >> 16);
}

__global__ void zero_kernel(int* p) { if (threadIdx.x == 0) *p = 0; }

// ---------------------------------------------------------------------------
// PACKED TILE LAYOUT (round 4): operands stored as [panel(128 rows)][ktile(64)]
// 16 KB contiguous tile-chunks, XOR chunk swizzle baked in:
//   element (row=n, k) -> u16 index
//     ((n>>7)*PK + (k>>6))*8192 + ((n&127)*8 + (((k>>3)&7) ^ (n&7)))*8 + (k&7)
// ---------------------------------------------------------------------------

// Convert both weight matrices fp32 -> packed-swizzled bf16 in one launch.
// Wfc: rows=FDIM, K=CDIM (PK=32). Wpr: rows=CDIM, K=FDIM (PK=128).
__global__ __launch_bounds__(256) void cvt2_kernel(
    const float* __restrict__ s1, unsigned short* __restrict__ d1,
    const float* __restrict__ s2, unsigned short* __restrict__ d2)
{
    const int NC1 = FDIM * (CDIM / 8);   // 16B chunks in matrix 1
    int i = blockIdx.x * 256 + threadIdx.x;
    const float* src; unsigned short* dst;
    int n, t, PK, K8;
    if (i < NC1) { src = s1; dst = d1; n = i >> 8; t = i & 255; PK = 32; K8 = 256; }
    else { i -= NC1; src = s2; dst = d2; n = i >> 10; t = i & 1023; PK = 128; K8 = 1024; }
    const int kt = t >> 3, q8 = t & 7;
    const int r = n & 127, ni = n >> 7;
    const float4* sp = (const float4*)src + ((size_t)n * K8 + t) * 2;
    float4 v0 = sp[0], v1 = sp[1];
    short8 o;
    o[0] = (short)f2bf(v0.x); o[1] = (short)f2bf(v0.y);
    o[2] = (short)f2bf(v0.z); o[3] = (short)f2bf(v0.w);
    o[4] = (short)f2bf(v1.x); o[5] = (short)f2bf(v1.y);
    o[6] = (short)f2bf(v1.z); o[7] = (short)f2bf(v1.w);
    size_t di = (((size_t)ni * PK + kt) * 128 + r) * 64 + (size_t)((q8 ^ (r & 7)) << 3);
    __builtin_nontemporal_store(o, (short8*)(dst + di));
}

// Per token: router logit, sigmoid mask, RMSNorm; compact selected tokens into
// Xn (bf16, PACKED, PK=32). ALL tokens get out = x (residual base); GEMM2
// atomic-adds scale*acc on top for selected tokens (split-K x2).
__global__ __launch_bounds__(256) void router_kernel(
    const float* __restrict__ x, const float* __restrict__ wr,
    float* __restrict__ out, unsigned short* __restrict__ Xn,
    int* __restrict__ idx, float* __restrict__ mv, int* __restrict__ cnt)
{
    const int token = blockIdx.x;
    const int tid = threadIdx.x;
    const float4* xr = (const float4*)(x + (size_t)token * CDIM);
    const float4* w4 = (const float4*)wr;
    // thread tid owns k = tid*8 .. tid*8+7  (one packed 16B chunk)
    float4 a0 = xr[2 * tid];
    float4 a1 = xr[2 * tid + 1];
    float4 b0 = w4[2 * tid];
    float4 b1 = w4[2 * tid + 1];
    float ss = a0.x*a0.x + a0.y*a0.y + a0.z*a0.z + a0.w*a0.w
             + a1.x*a1.x + a1.y*a1.y + a1.z*a1.z + a1.w*a1.w;
    float dt = a0.x*b0.x + a0.y*b0.y + a0.z*b0.z + a0.w*b0.w
             + a1.x*b1.x + a1.y*b1.y + a1.z*b1.z + a1.w*b1.w;
    #pragma unroll
    for (int off = 32; off > 0; off >>= 1) {
        ss += __shfl_down(ss, off);
        dt += __shfl_down(dt, off);
    }
    __shared__ float red_ss[4], red_dt[4];
    __shared__ float s_rms;
    __shared__ int s_pos;
    const int wave = tid >> 6;
    if ((tid & 63) == 0) { red_ss[wave] = ss; red_dt[wave] = dt; }
    __syncthreads();
    if (tid == 0) {
        float S = red_ss[0] + red_ss[1] + red_ss[2] + red_ss[3];
        float D = red_dt[0] + red_dt[1] + red_dt[2] + red_dt[3];
        float prob = 1.0f / (1.0f + expf(-D));
        s_rms = 1.0f / sqrtf(S * (1.0f / (float)CDIM) + EPSV);
        int pos = -1;
        if (prob > 0.5f) {
            pos = atomicAdd(cnt, 1);
            idx[pos] = token;
            mv[pos] = (1.0f + prob) - prob;  // replicate STE mask_i rounding exactly
        }
        s_pos = pos;
    }
    __syncthreads();
    const float rms = s_rms;
    const int pos = s_pos;
    float* op = out + (size_t)token * CDIM;
    // residual base for ALL tokens (GEMM2 atomic-adds on top for selected)
    f32x4 r0 = {a0.x, a0.y, a0.z, a0.w};
    f32x4 r1 = {a1.x, a1.y, a1.z, a1.w};
    __builtin_nontemporal_store(r0, (f32x4*)(op + tid * 8));
    __builtin_nontemporal_store(r1, (f32x4*)(op + tid * 8 + 4));
    if (pos >= 0) {
        // packed-swizzled write: chunk t=tid of compacted row pos
        const int kt = tid >> 3, q8 = tid & 7;
        const int r = pos & 127, mi = pos >> 7;
        short8 o;
        o[0] = (short)f2bf(a0.x * rms); o[1] = (short)f2bf(a0.y * rms);
        o[2] = (short)f2bf(a0.z * rms); o[3] = (short)f2bf(a0.w * rms);
        o[4] = (short)f2bf(a1.x * rms); o[5] = (short)f2bf(a1.y * rms);
        o[6] = (short)f2bf(a1.z * rms); o[7] = (short)f2bf(a1.w * rms);
        size_t di = (((size_t)mi * 32 + kt) * 128 + r) * 64 + (size_t)((q8 ^ (r & 7)) << 3);
        __builtin_nontemporal_store(o, (short8*)(Xn + di));
    }
}

// C[m][n] = sum_k A[m][k]*B[n][k]; A,B in PACKED tile layout.
//
// ROUND-7: 256x256 block tile, BK=64, 512 thr = 8 waves (2M x 4N), wave tile
// 128x64, acc[8][4]. Rationale (r6 cycle model): r6's 64x32 wave tile was
// LDS-BW-bound (0.75 KB LDS read/MFMA -> 2500 cyc LDS vs 1242 cyc MFMA per
// CU-kstep; measured wall 2531 cyc). 128x64 halves LDS reads/MFMA (0.375)
// and staged writes/MFMA (0.125) -> MFMA becomes the dominant term.
//
// Staging: reg-staged (r6-proven; global_load_lds caps outstanding reqs),
// 1 reg set, 2-deep LDS double buffer, raw s_barrier + lgkmcnt(0) only
// (never drains vmcnt -> loads stay in flight across barriers).
//   iter kt: ds_write set -> lds[(kt+1)&1]   (vmcnt waits auto, counted)
//            issue loads tile kt+2 -> set    (fly across compute+barrier)
//            compute lds[kt&1]; lgkmcnt(0); s_barrier
// LDS = 2 x 64 KB (dynamic 128 KB, 1 block/CU).
//
// Raster: r0-style m-fastest 8x8 supertile (measured-best FETCH).
// MODE 1: Hout = bf16(relu(acc)^2) in PACKED layout (GEMM2's A, PK=128).
// MODE 2: atomicAdd(out[token][n], scale*acc), split-K via blockIdx.z.
template <int K, int MODE, int LDO, int KSPLIT>
__global__ __launch_bounds__(512, 2) void gemm_bt(
    const unsigned short* __restrict__ A,
    const unsigned short* __restrict__ B,
    unsigned short* __restrict__ Hout,
    float* __restrict__ out,
    const int* __restrict__ idx,
    const float* __restrict__ mv,
    const int* __restrict__ cntp)
{
    const int cnt = *cntp;
    // supertile raster: gridDim.x == 32 m-panels (256 rows each)
    const int bid = blockIdx.y * 32 + blockIdx.x;
    const int s = bid >> 6;
    const int w = bid & 63;
    const int mi = (s & 3) * 8 + (w & 7);    // m-fastest
    const int ni = (s >> 2) * 8 + (w >> 3);
    const int m0 = mi * 256;
    if (m0 >= cnt) return;
    const int n0 = ni * 256;
    const int k0 = (int)blockIdx.z * (K / KSPLIT);

    extern __shared__ unsigned short lds[];  // [2][A 16K u16 | B 16K u16] = 128 KB

    const int tid = threadIdx.x;
    const int wave = tid >> 6;
    const int lane = tid & 63;
    const int wm = (wave >> 2) * 128;        // 2 wave-rows (M)
    const int wn = (wave & 3) * 64;          // 4 wave-cols (N)
    const int quad = lane >> 4;
    const int l16 = lane & 15;

    constexpr int PK = K / 64;
    constexpr int NT = K / (64 * KSPLIT);

    // staging sources: 4 chunks/thread/operand; chunk c = tid + j*512;
    // half (c>>10) selects panel 2mi / 2mi+1; LDS dest = c*16B (linear).
    const unsigned short* aSrc[4];
    const unsigned short* bSrc[4];
    #pragma unroll
    for (int j = 0; j < 4; ++j) {
        const int c = tid + j * 512;
        aSrc[j] = A + ((size_t)(2 * mi + (c >> 10)) * PK + (k0 >> 6)) * 8192
                    + (size_t)(c & 1023) * 8;
        bSrc[j] = B + ((size_t)(2 * ni + (c >> 10)) * PK + (k0 >> 6)) * 8192
                    + (size_t)(c & 1023) * 8;
    }

    short8 ar[4], br[4];

    auto LOAD = [&](int kt) {
        #pragma unroll
        for (int j = 0; j < 4; ++j) {
            ar[j] = *(const short8*)(aSrc[j] + (size_t)kt * 8192);
            br[j] = *(const short8*)(bSrc[j] + (size_t)kt * 8192);
        }
    };
    auto WRITE = [&](int buf) {
        unsigned short* base = &lds[buf * 32768];
        #pragma unroll
        for (int j = 0; j < 4; ++j) {
            const int c = tid + j * 512;
            *(short8*)&base[(size_t)c * 8] = ar[j];
            *(short8*)&base[16384 + (size_t)c * 8] = br[j];
        }
    };

    floatx4 acc[8][4] = {};

    auto COMPUTE = [&](int buf) {
        const unsigned short* bA = &lds[buf * 32768];
        const unsigned short* bB = &lds[buf * 32768 + 16384];
        #pragma unroll
        for (int st = 0; st < 2; ++st) {
            frag_t af[8], bf[4];
            #pragma unroll
            for (int m = 0; m < 8; ++m) {
                const int ra = wm + m * 16 + l16;
                af[m] = *(const frag_t*)&bA[(ra >> 7) * 8192 + (ra & 127) * 64
                                            + (((st * 4 + quad) ^ (ra & 7)) << 3)];
            }
            #pragma unroll
            for (int n = 0; n < 4; ++n) {
                const int rb = wn + n * 16 + l16;
                bf[n] = *(const frag_t*)&bB[(rb >> 7) * 8192 + (rb & 127) * 64
                                            + (((st * 4 + quad) ^ (rb & 7)) << 3)];
            }
            #pragma unroll
            for (int m = 0; m < 8; ++m)
                #pragma unroll
                for (int n = 0; n < 4; ++n)
                    acc[m][n] = mfma_bf16(af[m], bf[n], acc[m][n]);
        }
    };

    // prologue
    LOAD(0);
    WRITE(0);                 // compiler inserts counted vmcnt for ar/br
    if (NT > 1) LOAD(1);
    asm volatile("s_waitcnt lgkmcnt(0)" ::: "memory");
    __builtin_amdgcn_s_barrier();
    asm volatile("" ::: "memory");

    for (int kt = 0; kt < NT; ++kt) {
        if (kt + 1 < NT) WRITE((kt + 1) & 1);
        if (kt + 2 < NT) LOAD(kt + 2);      // in flight across compute+barrier
        COMPUTE(kt & 1);
        asm volatile("s_waitcnt lgkmcnt(0)" ::: "memory");
        __builtin_amdgcn_s_barrier();
        asm volatile("" ::: "memory");
    }

    // C/D layout (verified m89/m91): col(n) = lane&15, row(m) = quad*4 + reg
    if (MODE == 1) {
        constexpr int PKH = LDO / 64;   // H packed with K = LDO = FDIM
        #pragma unroll
        for (int tm = 0; tm < 8; ++tm) {
            const int rbase = wm + tm * 16 + quad * 4;  // row in 256-row tile
            #pragma unroll
            for (int tn = 0; tn < 4; ++tn) {
                const int gn = n0 + wn + tn * 16 + l16;
                const int kth = gn >> 6, q8 = (gn >> 3) & 7, e = gn & 7;
                #pragma unroll
                for (int v = 0; v < 4; ++v) {
                    const int r = rbase + v;
                    const int gr = m0 + r;
                    float h = fmaxf(acc[tm][tn][v], 0.0f);  // eats NaN pad rows
                    size_t di = (((size_t)(gr >> 7) * PKH + kth) * 128 + (gr & 127)) * 64
                              + (size_t)((q8 ^ (gr & 7)) << 3) + e;
                    __builtin_nontemporal_store(f2bf(h * h), &Hout[di]);
                }
            }
        }
    } else {
        #pragma unroll
        for (int tm = 0; tm < 8; ++tm) {
            const int gmb = m0 + wm + tm * 16 + quad * 4;
            #pragma unroll
            for (int v = 0; v < 4; ++v) {
                const int gm = gmb + v;
                if (gm < cnt) {  // never read poisoned idx/mv beyond cnt
                    const int token = idx[gm];
                    const float scale = mv[gm];
                    float* orow = out + (size_t)token * LDO;
                    #pragma unroll
                    for (int tn = 0; tn < 4; ++tn) {
                        const int gn = n0 + wn + tn * 16 + l16;
                        atomicAdd(&orow[gn], scale * acc[tm][tn][v]);
                    }
                }
            }
        }
    }
}

extern "C" void kernel_launch(void* const* d_in, const int* in_sizes, int n_in,
                              void* d_out, int out_size, void* d_ws, size_t ws_size,
                              hipStream_t stream)
{
    const float* x   = (const float*)d_in[0];
    const float* wfc = (const float*)d_in[1];
    const float* wpr = (const float*)d_in[2];
    const float* wrt = (const float*)d_in[3];
    float* out = (float*)d_out;

    // ws layout (bytes): [cnt 256][idx 32K][mv 32K][Xn 32M][Wfc 32M][Wpr 32M][H 128M]
    char* ws = (char*)d_ws;
    int*   cnt = (int*)ws;
    int*   idx = (int*)(ws + 256);
    float* mv  = (float*)(ws + 256 + 32768);
    unsigned short* Xn  = (unsigned short*)(ws + 65792);
    unsigned short* Wfc = (unsigned short*)(ws + 65792 + 33554432ULL);
    unsigned short* Wpr = (unsigned short*)(ws + 65792 + 67108864ULL);
    unsigned short* H   = (unsigned short*)(ws + 65792 + 100663296ULL);

    const int nchunks = FDIM * (CDIM / 8) + CDIM * (FDIM / 8);
    zero_kernel<<<1, 64, 0, stream>>>(cnt);
    cvt2_kernel<<<nchunks / 256, 256, 0, stream>>>(wfc, Wfc, wpr, Wpr);
    router_kernel<<<TOKENS, 256, 0, stream>>>(x, wrt, out, Xn, idx, mv, cnt);
    // GEMM1: H[m][f] = relu(Xn @ Wfc^T)^2, M=cnt (<=8192), N=8192, K=2048
    gemm_bt<CDIM, 1, FDIM, 1><<<dim3(32, FDIM / 256), 512, 131072, stream>>>(
        Xn, Wfc, H, nullptr, nullptr, nullptr, cnt);
    // GEMM2: out[token][c] += mask_i*(H @ Wpr^T), M=cnt, N=2048, K=8192, split-K x2
    gemm_bt<FDIM, 2, CDIM, 2><<<dim3(32, CDIM / 256, 2), 512, 131072, stream>>>(
        H, Wpr, nullptr, out, idx, mv, cnt);
}